// Round 10
// baseline (508.772 us; speedup 1.0000x reference)
//
#include <hip/hip_runtime.h>

#define R_RAYS 16384
#define Z_ALL 192
#define WEPS 1e-5f
#define REPS 3          // diagnostic: repeat body to surface our dispatch in rocprof top-k

typedef float f32x4 __attribute__((ext_vector_type(4)));

__device__ __forceinline__ float uval(int j) {
    return (j == 127) ? 1.0f : (float)j * (1.0f / 127.0f);
}

__global__ __launch_bounds__(256, 8) void ray_sampler_kernel(
    const float* __restrict__ rays_d,
    const float* __restrict__ rays_o,
    const float* __restrict__ z_vals,
    const float* __restrict__ weights,
    float* __restrict__ pts_out,
    float* __restrict__ zall_out)
{
    __shared__ __align__(16) float s_za[4][Z_ALL];   // wave-private slices

    const int wid  = threadIdx.x >> 6;
    const int lane = threadIdx.x & 63;
    const int ray  = blockIdx.x * 4 + wid;
    const int r    = ray & (R_RAYS - 1);

    // ---- load inputs once ----
    float ox = rays_o[ray * 3 + 0], oy = rays_o[ray * 3 + 1], oz = rays_o[ray * 3 + 2];
    float dx = rays_d[ray * 3 + 0], dy = rays_d[ray * 3 + 1], dz = rays_d[ray * 3 + 2];
    float zv0 = z_vals[r * 64 + lane];
    float w0  = (lane < 62) ? weights[(size_t)ray * 64 + lane + 1] : 0.0f;

    #pragma unroll 1
    for (int rep = 0; rep < REPS; ++rep) {
        float zv = zv0, w = w0;
        // identity barrier: forces full recompute each rep (no CSE), values unchanged
        asm volatile("" : "+v"(zv), "+v"(w));

        float zv1 = __shfl_down(zv, 1);
        float zv2 = __shfl_down(zv, 2);
        float zh  = 0.5f * (zv + zv1);
        float zh1 = 0.5f * (zv1 + zv2);

        float wp = (lane < 62) ? w + WEPS : 0.0f;
        float sc = wp;
        #pragma unroll
        for (int off = 1; off < 64; off <<= 1) {
            float y = __shfl_up(sc, off);
            if (lane >= off) sc += y;
        }
        float total = __shfl(sc, 61);
        float scp   = __shfl_up(sc, 1);
        float clo = (lane == 0) ? 0.0f : scp / total;
        float chi = sc / total;
        float denom = chi - clo;
        float rden  = (denom < 1e-5f) ? 1.0f : 1.0f / denom;
        float bhi = (lane >= 62) ? zh : zh1;

        int js = (int)ceilf(clo * 127.0f);
        js = js < 0 ? 0 : (js > 128 ? 128 : js);
        while (js > 0 && uval(js - 1) >= clo) --js;
        while (js < 128 && uval(js) < clo) ++js;
        int jn = __shfl_down(js, 1);
        int je = (lane == 62) ? 128 : ((lane > 62) ? js : jn);

        int cnt_lt = 0;
        for (int j = js; j < je; ++j) {
            float u = uval(j);
            float t = (u - clo) * rden;
            float s = fmaf(t, bhi - zh, zh);
            int ind = (zv1 <= s) ? 1 : 0;
            cnt_lt += 1 - ind;
            s_za[wid][j + lane + 1 + ind] = s;
        }
        if (lane == 0) s_za[wid][0] = zv;
        if (lane <= 62) s_za[wid][lane + 1 + js + cnt_lt] = zv1;

        // ---- zero-divide drain ----
        // lanes 0..47: pts samples 4i..4i+3 -> floats 12i..12i+11 (3 f32x4)
        // lanes 48..63: z_all floats 12j..12j+11 (3 f32x4), j = lane-48
        const float* za = s_za[wid];
        if (lane < 48) {
            f32x4 z = *(const f32x4*)&za[lane * 4];       // z0..z3
            float* p = pts_out + (size_t)ray * (Z_ALL * 3) + lane * 12;
            f32x4 v0, v1, v2;
            v0[0] = fmaf(z[0], dx, ox); v0[1] = fmaf(z[0], dy, oy);
            v0[2] = fmaf(z[0], dz, oz); v0[3] = fmaf(z[1], dx, ox);
            v1[0] = fmaf(z[1], dy, oy); v1[1] = fmaf(z[1], dz, oz);
            v1[2] = fmaf(z[2], dx, ox); v1[3] = fmaf(z[2], dy, oy);
            v2[0] = fmaf(z[2], dz, oz); v2[1] = fmaf(z[3], dx, ox);
            v2[2] = fmaf(z[3], dy, oy); v2[3] = fmaf(z[3], dz, oz);
            *(f32x4*)(p + 0) = v0;
            *(f32x4*)(p + 4) = v1;
            *(f32x4*)(p + 8) = v2;
        } else {
            int j = lane - 48;                            // 0..15
            const float* zsrc = &za[j * 12];
            float* q = zall_out + (size_t)ray * Z_ALL + j * 12;
            f32x4 a = *(const f32x4*)(zsrc + 0);
            f32x4 b = *(const f32x4*)(zsrc + 4);
            f32x4 c = *(const f32x4*)(zsrc + 8);
            *(f32x4*)(q + 0) = a;
            *(f32x4*)(q + 4) = b;
            *(f32x4*)(q + 8) = c;
        }
    }
}

extern "C" void kernel_launch(void* const* d_in, const int* in_sizes, int n_in,
                              void* d_out, int out_size, void* d_ws, size_t ws_size,
                              hipStream_t stream) {
    const float* rays_d  = (const float*)d_in[0];
    const float* rays_o  = (const float*)d_in[1];
    const float* z_vals  = (const float*)d_in[2];
    const float* weights = (const float*)d_in[3];

    float* pts  = (float*)d_out;                       // (8,16384,192,3)
    float* zall = pts + (size_t)8 * 16384 * 192 * 3;   // (8,16384,192)

    const int total_rays = 8 * 16384;                  // 131072
    dim3 grid(total_rays / 4), block(256);
    ray_sampler_kernel<<<grid, block, 0, stream>>>(rays_d, rays_o, z_vals,
                                                   weights, pts, zall);
}

// Round 11
// 401.029 us; speedup vs baseline: 1.2687x; 1.2687x over previous
//
#include <hip/hip_runtime.h>

#define R_RAYS 16384
#define Z_ALL 192
#define WEPS 1e-5f
#define NBLK 2048       // 2048 blocks x 4 waves = 8192 waves resident (32/CU)
#define ITERS 16        // 8192 waves x 16 iters = 131072 rays, dense moving window

typedef float f32x4 __attribute__((ext_vector_type(4)));

__device__ __forceinline__ float uval(int j) {
    return (j == 127) ? 1.0f : (float)j * (1.0f / 127.0f);
}

__global__ __launch_bounds__(256, 8) void ray_sampler_kernel(
    const float* __restrict__ rays_d,
    const float* __restrict__ rays_o,
    const float* __restrict__ z_vals,
    const float* __restrict__ weights,
    float* __restrict__ pts_out,
    float* __restrict__ zall_out)
{
    __shared__ __align__(16) float s_za[4][Z_ALL];   // wave-private slices

    const int wid  = threadIdx.x >> 6;
    const int lane = threadIdx.x & 63;
    const int gw   = blockIdx.x * 4 + wid;           // 0..8191

    #pragma unroll 1
    for (int it = 0; it < ITERS; ++it) {
        const int ray = it * 8192 + gw;              // dense window per iter
        const int r   = ray & (R_RAYS - 1);

        // ---- inputs ----
        float zv = z_vals[r * 64 + lane];
        float w  = (lane < 62) ? weights[(size_t)ray * 64 + lane + 1] : 0.0f;
        float ox = rays_o[ray * 3 + 0], oy = rays_o[ray * 3 + 1], oz = rays_o[ray * 3 + 2];
        float dx = rays_d[ray * 3 + 0], dy = rays_d[ray * 3 + 1], dz = rays_d[ray * 3 + 2];

        // ---- per-lane register state ----
        float zv1 = __shfl_down(zv, 1);
        float zv2 = __shfl_down(zv, 2);
        float zh  = 0.5f * (zv + zv1);        // bins[l]   (valid l<=62)
        float zh1 = 0.5f * (zv1 + zv2);       // bins[l+1] (valid l<=61)

        // ---- weights scan -> cdf interval [clo, chi) per lane ----
        float wp = (lane < 62) ? w + WEPS : 0.0f;
        float sc = wp;
        #pragma unroll
        for (int off = 1; off < 64; off <<= 1) {
            float y = __shfl_up(sc, off);
            if (lane >= off) sc += y;
        }
        float total  = __shfl(sc, 61);
        float rtotal = 1.0f / total;
        float scp    = __shfl_up(sc, 1);
        float clo = (lane == 0) ? 0.0f : scp * rtotal;   // cdf[l]
        float chi = sc * rtotal;                          // cdf[l+1]
        float denom = chi - clo;
        float rden  = (denom < 1e-5f) ? 1.0f : 1.0f / denom;
        float bhi = (lane >= 62) ? zh : zh1;

        // ---- ownership: js = min j with u_j >= clo ----
        int js = (int)ceilf(clo * 127.0f);
        js = js < 0 ? 0 : (js > 128 ? 128 : js);
        while (js > 0 && uval(js - 1) >= clo) --js;
        while (js < 128 && uval(js) < clo) ++js;
        int jn = __shfl_down(js, 1);
        int je = (lane == 62) ? 128 : ((lane > 62) ? js : jn);

        // ---- emit owned samples directly at final merged rank ----
        int cnt_lt = 0;
        for (int j = js; j < je; ++j) {
            float u = uval(j);
            float t = (u - clo) * rden;
            float s = fmaf(t, bhi - zh, zh);
            int ind = (zv1 <= s) ? 1 : 0;
            cnt_lt += 1 - ind;
            s_za[wid][j + lane + 1 + ind] = s;
        }
        if (lane == 0) s_za[wid][0] = zv;
        if (lane <= 62) s_za[wid][lane + 1 + js + cnt_lt] = zv1;

        // ---- zero-divide drain (nt stores) ----
        // lanes 0..47: pts for samples 4i..4i+3 -> floats 12i..12i+11
        // lanes 48..63: z_all floats 12j..12j+11, j = lane-48
        const float* za = s_za[wid];
        if (lane < 48) {
            f32x4 z = *(const f32x4*)&za[lane * 4];
            float* p = pts_out + (size_t)ray * (Z_ALL * 3) + lane * 12;
            f32x4 v0, v1, v2;
            v0[0] = fmaf(z[0], dx, ox); v0[1] = fmaf(z[0], dy, oy);
            v0[2] = fmaf(z[0], dz, oz); v0[3] = fmaf(z[1], dx, ox);
            v1[0] = fmaf(z[1], dy, oy); v1[1] = fmaf(z[1], dz, oz);
            v1[2] = fmaf(z[2], dx, ox); v1[3] = fmaf(z[2], dy, oy);
            v2[0] = fmaf(z[2], dz, oz); v2[1] = fmaf(z[3], dx, ox);
            v2[2] = fmaf(z[3], dy, oy); v2[3] = fmaf(z[3], dz, oz);
            __builtin_nontemporal_store(v0, (f32x4*)(p + 0));
            __builtin_nontemporal_store(v1, (f32x4*)(p + 4));
            __builtin_nontemporal_store(v2, (f32x4*)(p + 8));
        } else {
            int j = lane - 48;                            // 0..15
            const float* zsrc = &za[j * 12];
            float* q = zall_out + (size_t)ray * Z_ALL + j * 12;
            f32x4 a = *(const f32x4*)(zsrc + 0);
            f32x4 b = *(const f32x4*)(zsrc + 4);
            f32x4 c = *(const f32x4*)(zsrc + 8);
            __builtin_nontemporal_store(a, (f32x4*)(q + 0));
            __builtin_nontemporal_store(b, (f32x4*)(q + 4));
            __builtin_nontemporal_store(c, (f32x4*)(q + 8));
        }
    }
}

extern "C" void kernel_launch(void* const* d_in, const int* in_sizes, int n_in,
                              void* d_out, int out_size, void* d_ws, size_t ws_size,
                              hipStream_t stream) {
    const float* rays_d  = (const float*)d_in[0];
    const float* rays_o  = (const float*)d_in[1];
    const float* z_vals  = (const float*)d_in[2];
    const float* weights = (const float*)d_in[3];

    float* pts  = (float*)d_out;                       // (8,16384,192,3)
    float* zall = pts + (size_t)8 * 16384 * 192 * 3;   // (8,16384,192)

    dim3 grid(NBLK), block(256);
    ray_sampler_kernel<<<grid, block, 0, stream>>>(rays_d, rays_o, z_vals,
                                                   weights, pts, zall);
}

// Round 12
// 85.192 us; speedup vs baseline: 5.9720x; 4.7073x over previous
//
#include <hip/hip_runtime.h>

#define R_RAYS 16384
#define Z_ALL 192
#define WEPS 1e-5f

typedef float f32x4 __attribute__((ext_vector_type(4)));

__device__ __forceinline__ float uval(int j) {
    return (j == 127) ? 1.0f : (float)j * (1.0f / 127.0f);
}

__global__ __launch_bounds__(256, 8) void ray_sampler_kernel(
    const float* __restrict__ rays_d,
    const float* __restrict__ rays_o,
    const float* __restrict__ z_vals,
    const float* __restrict__ weights,
    float* __restrict__ pts_out,
    float* __restrict__ zall_out)
{
    __shared__ __align__(16) float s_za[4][Z_ALL];    // merged z (wave-private)
    __shared__ __align__(16) float s_pts[4][Z_ALL*3]; // pts staged in final layout

    const int wid  = threadIdx.x >> 6;
    const int lane = threadIdx.x & 63;
    const int ray  = blockIdx.x * 4 + wid;
    const int r    = ray & (R_RAYS - 1);

    // ---- inputs ----
    float zv = z_vals[r * 64 + lane];
    float w  = (lane < 62) ? weights[(size_t)ray * 64 + lane + 1] : 0.0f;
    float ox = rays_o[ray * 3 + 0], oy = rays_o[ray * 3 + 1], oz = rays_o[ray * 3 + 2];
    float dx = rays_d[ray * 3 + 0], dy = rays_d[ray * 3 + 1], dz = rays_d[ray * 3 + 2];

    // ---- per-lane register state ----
    float zv1 = __shfl_down(zv, 1);
    float zv2 = __shfl_down(zv, 2);
    float zh  = 0.5f * (zv + zv1);        // bins[l]   (valid l<=62)
    float zh1 = 0.5f * (zv1 + zv2);       // bins[l+1] (valid l<=61)

    // ---- weights scan -> cdf interval [clo, chi) per lane ----
    float wp = (lane < 62) ? w + WEPS : 0.0f;
    float sc = wp;
    #pragma unroll
    for (int off = 1; off < 64; off <<= 1) {
        float y = __shfl_up(sc, off);
        if (lane >= off) sc += y;
    }
    float total  = __shfl(sc, 61);
    float rtotal = 1.0f / total;
    float scp    = __shfl_up(sc, 1);
    float clo = (lane == 0) ? 0.0f : scp * rtotal;   // cdf[l]
    float chi = sc * rtotal;                          // cdf[l+1]
    float denom = chi - clo;
    float rden  = (denom < 1e-5f) ? 1.0f : 1.0f / denom;
    float bhi = (lane >= 62) ? zh : zh1;

    // ---- ownership: js = min j with u_j >= clo ----
    int js = (int)ceilf(clo * 127.0f);
    js = js < 0 ? 0 : (js > 128 ? 128 : js);
    while (js > 0 && uval(js - 1) >= clo) --js;
    while (js < 128 && uval(js) < clo) ++js;
    int jn = __shfl_down(js, 1);
    int je = (lane == 62) ? 128 : ((lane > 62) ? js : jn);

    // ---- emit owned samples directly at final merged rank ----
    int cnt_lt = 0;
    for (int j = js; j < je; ++j) {
        float u = uval(j);
        float t = (u - clo) * rden;
        float s = fmaf(t, bhi - zh, zh);
        int ind = (zv1 <= s) ? 1 : 0;
        cnt_lt += 1 - ind;
        s_za[wid][j + lane + 1 + ind] = s;
    }
    if (lane == 0) s_za[wid][0] = zv;
    if (lane <= 62) s_za[wid][lane + 1 + js + cnt_lt] = zv1;

    // ---- stage pts into LDS in final interleaved layout ----
    // lane handles samples lane, lane+64, lane+128: 3 fmafs each, stride-3 LDS
    // writes (gcd(3,32)=1 -> conflict-free 2-way)
    const float* za = s_za[wid];
    float* sp = s_pts[wid];
    #pragma unroll
    for (int k = 0; k < 3; ++k) {
        int sidx = lane + 64 * k;
        float z = za[sidx];
        sp[sidx * 3 + 0] = fmaf(z, dx, ox);
        sp[sidx * 3 + 1] = fmaf(z, dy, oy);
        sp[sidx * 3 + 2] = fmaf(z, dz, oz);
    }

    // ---- pure-copy drain: dense 16B/lane per instruction, nt stores ----
    // t=0: pts floats [0..255]; t=1: [256..511];
    // t=2: lanes 0..15 pts [512..575], lanes 16..63 zall [0..191]
    const size_t pbase = (size_t)ray * (Z_ALL * 3);
    const size_t zbase = (size_t)ray * Z_ALL;
    #pragma unroll
    for (int t = 0; t < 3; ++t) {
        int idx = lane + 64 * t;                  // 0..191
        if (idx < 144) {
            f32x4 v = *(const f32x4*)&sp[idx * 4];
            __builtin_nontemporal_store(v, (f32x4*)(pts_out + pbase + idx * 4));
        } else {
            int j = idx - 144;                    // 0..47
            f32x4 v = *(const f32x4*)&za[j * 4];
            __builtin_nontemporal_store(v, (f32x4*)(zall_out + zbase + j * 4));
        }
    }
}

extern "C" void kernel_launch(void* const* d_in, const int* in_sizes, int n_in,
                              void* d_out, int out_size, void* d_ws, size_t ws_size,
                              hipStream_t stream) {
    const float* rays_d  = (const float*)d_in[0];
    const float* rays_o  = (const float*)d_in[1];
    const float* z_vals  = (const float*)d_in[2];
    const float* weights = (const float*)d_in[3];

    float* pts  = (float*)d_out;                       // (8,16384,192,3)
    float* zall = pts + (size_t)8 * 16384 * 192 * 3;   // (8,16384,192)

    const int total_rays = 8 * 16384;                  // 131072
    dim3 grid(total_rays / 4), block(256);
    ray_sampler_kernel<<<grid, block, 0, stream>>>(rays_d, rays_o, z_vals,
                                                   weights, pts, zall);
}